// Round 1
// baseline (157.112 us; speedup 1.0000x reference)
//
#include <hip/hip_runtime.h>

typedef unsigned char u8;
typedef float fp32x4 __attribute__((ext_vector_type(4)));

#define BS 4096
#define NROW 8192
#define D 512
#define TILE 128
#define NB (NROW / TILE)          // 64 block-rows/cols
#define NBLK (NB * (NB + 1) / 2)  // 2080 upper-triangle tiles
#define NPBLK 256                 // persistent workgroups (1 per CU)
#define INV_T 10.0f

// Packed An layout (we control both producer and consumer):
//   offset(row, k) = (row>>4)*8192 + (k>>5)*512 + (row&15)*32 + (k&31)
// Properties:
//  - a 128-row strip = 8 groups = 65536 CONTIGUOUS bytes -> linear g2l staging
//  - MFMA fp8 16x16x32 A/B frag for lane(fr=l&15, h=l>>4), group gi, kstep ks
//    is the 8 bytes at  gi*8192 + ks*512 + fr*32 + h*8  -> ds_read_b64 with
//    one base VGPR + compile-time immediate; wave pattern = uniform 4
//    words/bank (the structural floor for a 512B wave read, no conflicts).

__device__ __forceinline__ void g2l16(const void* g, void* l) {
  __builtin_amdgcn_global_load_lds(
      (const __attribute__((address_space(1))) unsigned int*)g,
      (__attribute__((address_space(3))) unsigned int*)l, 16, 0, 0);
}

// stage one 128-row strip (64 KB contiguous) into LDS; 16 g2l16 per thread
__device__ __forceinline__ void stage_strip(const u8* __restrict__ g,
                                            u8* __restrict__ l, int tid) {
#pragma unroll
  for (int it = 0; it < 16; ++it)
    g2l16(g + it * 4096 + tid * 16, l + it * 4096 + tid * 16);
}

// Wave-per-row normalize -> fp8 e4m3, written in packed layout.
// Also zeroes den/posAcc (ws is re-poisoned before every launch).
__global__ __launch_bounds__(256) void normalize_k(
    const float* __restrict__ zi, const float* __restrict__ zj,
    u8* __restrict__ An, float* __restrict__ den, float* __restrict__ posAcc) {
  const int lane = threadIdx.x & 63;
  const int wave = threadIdx.x >> 6;
  const int r = blockIdx.x * 4 + wave;
  const float* src = (r < BS) ? (zi + (size_t)r * D) : (zj + (size_t)(r - BS) * D);
  const float4 v0 = ((const float4*)src)[lane * 2];
  const float4 v1 = ((const float4*)src)[lane * 2 + 1];
  float ss = v0.x * v0.x + v0.y * v0.y + v0.z * v0.z + v0.w * v0.w +
             v1.x * v1.x + v1.y * v1.y + v1.z * v1.z + v1.w * v1.w;
#pragma unroll
  for (int off = 1; off < 64; off <<= 1) ss += __shfl_xor(ss, off);
  const float inv = 1.0f / fmaxf(sqrtf(ss), 1e-8f);
  int lo = __builtin_amdgcn_cvt_pk_fp8_f32(v0.x * inv, v0.y * inv, 0, false);
  lo = __builtin_amdgcn_cvt_pk_fp8_f32(v0.z * inv, v0.w * inv, lo, true);
  int hi = __builtin_amdgcn_cvt_pk_fp8_f32(v1.x * inv, v1.y * inv, 0, false);
  hi = __builtin_amdgcn_cvt_pk_fp8_f32(v1.z * inv, v1.w * inv, hi, true);
  // lane holds k = 8*lane .. 8*lane+8  ->  ks = lane>>2, byte-in-32 = (lane&3)*8
  const int off = ((r >> 4) << 13) + ((lane >> 2) << 9) + ((r & 15) << 5) +
                  ((lane & 3) << 3);
  *(int2*)(An + off) = make_int2(lo, hi);
  if (lane == 0) den[r] = 0.0f;
  if (r == 0 && lane == 0) posAcc[0] = 0.0f;
}

// Persistent full-K GEMM: each block owns a contiguous chunk of ~8 triangle
// tiles. LDS holds full-K A and B strips (64 KB each) -> the K loop has ZERO
// barriers (256 MFMA back-to-back per wave). Per tile:
//   compute -> barrier -> issue next-tile DMA -> epilogue (overlaps DMA)
//   -> barrier (drains vmcnt; next tile staged).
// A-strip restaged only when bi changes (chunks are triangle-contiguous).
__global__ __launch_bounds__(256) void gemm_expsum(
    const u8* __restrict__ An, float* __restrict__ den,
    float* __restrict__ posAcc) {
  __shared__ __align__(16) u8 sA[TILE * D];  // 64 KB
  __shared__ __align__(16) u8 sB[TILE * D];  // 64 KB

  const int tid = threadIdx.x;
  const int lane = tid & 63;
  const int wave = tid >> 6;
  const int wr = wave >> 1;  // wave tile 64x64 within the 128x128 block tile
  const int wc = wave & 1;
  const int fr = lane & 15;
  const int h = lane >> 4;

  // contiguous chunk [t0, t1) of triangle tiles (8 or 9 per block)
  const int t0 = (int)(((long)blockIdx.x * NBLK) >> 8);
  const int t1 = (int)(((long)(blockIdx.x + 1) * NBLK) >> 8);

  int rem = t0, bi = 0;
  while (rem >= NB - bi) { rem -= NB - bi; ++bi; }
  int bj = bi + rem;

  stage_strip(An + (size_t)bi * 65536, sA, tid);
  stage_strip(An + (size_t)bj * 65536, sB, tid);
  __syncthreads();  // drains vmcnt -> tiles resident

  const u8* pa = sA + wr * 32768 + fr * 32 + h * 8;
  const u8* pb = sB + wc * 32768 + fr * 32 + h * 8;

  for (int t = t0; t < t1; ++t) {
    fp32x4 acc[4][4] = {};
    // full-K compute: no barriers, no address VALU (all immediate offsets)
#pragma unroll
    for (int ks = 0; ks < 16; ++ks) {
      long a[4], b[4];
#pragma unroll
      for (int i = 0; i < 4; ++i) {
        a[i] = *(const long*)(pa + i * 8192 + ks * 512);
        b[i] = *(const long*)(pb + i * 8192 + ks * 512);
      }
#pragma unroll
      for (int i = 0; i < 4; ++i)
#pragma unroll
        for (int j = 0; j < 4; ++j)
          acc[i][j] = __builtin_amdgcn_mfma_f32_16x16x32_fp8_fp8(
              a[i], b[j], acc[i][j], 0, 0, 0);
    }
    __syncthreads();  // every wave done reading sA/sB

    // issue next tile's staging NOW; the DMA runs under the epilogue below
    int nbi = bi, nbj = bj + 1;
    if (nbj == NB) { ++nbi; nbj = nbi; }
    if (t + 1 < t1) {
      if (nbi != bi) stage_strip(An + (size_t)nbi * 65536, sA, tid);
      stage_strip(An + (size_t)nbj * 65536, sB, tid);
    }

    // Epilogue (register-only + atomics; safe while DMA overwrites LDS).
    // C/D layout: col = lane&15, row = (lane>>4)*4 + reg.
    const bool diag = (bi == bj);
    const int rowBase = bi * TILE;
    const int colBase = bj * TILE;
    const int rq = h * 4;
    float posPart = 0.0f;
    float colAcc[4] = {0.0f, 0.0f, 0.0f, 0.0f};
#pragma unroll
    for (int i = 0; i < 4; ++i) {
      const int rbase = rowBase + wr * 64 + i * 16 + rq;
      float rs[4] = {0.0f, 0.0f, 0.0f, 0.0f};
#pragma unroll
      for (int j = 0; j < 4; ++j) {
        const int colg = colBase + wc * 64 + j * 16 + fr;
        fp32x4 v = acc[i][j];
#pragma unroll
        for (int rg = 0; rg < 4; ++rg) {
          const int rowg = rbase + rg;
          const float sv = v[rg] * INV_T;
          float e = __expf(sv);
          if (diag && rowg == colg) e = 0.0f;  // exclude exact diagonal
          rs[rg] += e;
          colAcc[j] += e;
          if (colg == rowg + BS) posPart += sv;  // upper copy; doubled later
        }
      }
#pragma unroll
      for (int rg = 0; rg < 4; ++rg) {
        float s = rs[rg];
        s += __shfl_xor(s, 1);
        s += __shfl_xor(s, 2);
        s += __shfl_xor(s, 4);
        s += __shfl_xor(s, 8);
        if (fr == 0) atomicAdd(&den[rbase + rg], s);
      }
    }
    if (!diag) {
#pragma unroll
      for (int j = 0; j < 4; ++j) {
        float c = colAcc[j];
        c += __shfl_xor(c, 16);
        c += __shfl_xor(c, 32);
        if (h == 0) atomicAdd(&den[colBase + wc * 64 + j * 16 + fr], c);
      }
    }
    posPart += __shfl_xor(posPart, 1);
    posPart += __shfl_xor(posPart, 2);
    posPart += __shfl_xor(posPart, 4);
    posPart += __shfl_xor(posPart, 8);
    posPart += __shfl_xor(posPart, 16);
    posPart += __shfl_xor(posPart, 32);
    if (lane == 0 && posPart != 0.0f) atomicAdd(posAcc, posPart);

    __syncthreads();  // drains vmcnt -> next tile staged; LDS reuse safe
    bi = nbi;
    bj = nbj;
  }
}

__global__ __launch_bounds__(256) void finalize_k(
    const float* __restrict__ den, const float* __restrict__ posAcc,
    float* __restrict__ out) {
  const int t = threadIdx.x;
  float s = 0.0f;
  for (int i = t; i < NROW; i += 256) s += logf(den[i]);
#pragma unroll
  for (int off = 1; off < 64; off <<= 1) s += __shfl_xor(s, off);
  __shared__ float ws[4];
  if ((t & 63) == 0) ws[t >> 6] = s;
  __syncthreads();
  if (t == 0) {
    const float tot = ws[0] + ws[1] + ws[2] + ws[3];
    // each unordered positive pair was counted once -> double it
    out[0] = (tot - 2.0f * posAcc[0]) * (1.0f / (float)NROW);
  }
}

extern "C" void kernel_launch(void* const* d_in, const int* in_sizes, int n_in,
                              void* d_out, int out_size, void* d_ws, size_t ws_size,
                              hipStream_t stream) {
  const float* zi = (const float*)d_in[0];
  const float* zj = (const float*)d_in[1];
  float* out = (float*)d_out;

  u8* An = (u8*)d_ws;                                      // 4 MB packed fp8
  float* den = (float*)((char*)d_ws + (size_t)NROW * D);   // 8192 fp32
  float* posAcc = den + NROW;                              // 1 fp32

  normalize_k<<<NROW / 4, 256, 0, stream>>>(zi, zj, An, den, posAcc);
  gemm_expsum<<<NPBLK, 256, 0, stream>>>(An, den, posAcc);
  finalize_k<<<1, 256, 0, stream>>>(den, posAcc, out);
}

// Round 2
// 138.702 us; speedup vs baseline: 1.1327x; 1.1327x over previous
//
#include <hip/hip_runtime.h>

typedef unsigned char u8;
typedef float fp32x4 __attribute__((ext_vector_type(4)));
typedef long lx2 __attribute__((ext_vector_type(2)));

#define BS 4096
#define NROW 8192
#define D 512
#define TILE 128
#define NB (NROW / TILE)          // 64 block-rows/cols
#define NBLK (NB * (NB + 1) / 2)  // 2080 upper-triangle tiles
#define NPBLK 256                 // persistent workgroups (1 per CU)
#define INV_T 10.0f

// Packed An layout (producer + staging + consumer all agree; staging is a
// LINEAR byte copy so the permutation lives only in this formula).
// 8-byte chunk L = k>>3 of row r lives at:
//   off(r, L) = (r>>4)*8192                     // 16-row group
//             + (L>>3)*1024                     // p-block (two MFMA k-steps)
//             + (r&15)*64                       // row segment
//             + (((L&3) ^ ((r&15)>>2)) << 4)    // XOR bank swizzle
//             + (((L>>2)&1) << 3)               // ks parity (subk)
// Consumer: lane (fr = l&15, h = l>>4) reads ONE ds_read_b128 per (i, p)
// covering ks=2p and ks=2p+1: addr = fr*64 + ((h ^ (fr>>2))&3)*16 + p*1024.
// Bank math per 16-lane quarter (h fixed): chunk residue mod 8 =
// 4*(fr&1) + ((h^(fr>>2))&3) -> bijective over (fr&1, fr>>2), 2 lanes per
// residue -> every bank gets exactly 2 words = structural floor, 0 conflicts.

__device__ __forceinline__ void g2l16(const void* g, void* l) {
  __builtin_amdgcn_global_load_lds(
      (const __attribute__((address_space(1))) unsigned int*)g,
      (__attribute__((address_space(3))) unsigned int*)l, 16, 0, 0);
}

// stage one 128-row strip (64 KB contiguous) into LDS; 16 g2l16 per thread
__device__ __forceinline__ void stage_strip(const u8* __restrict__ g,
                                            u8* __restrict__ l, int tid) {
#pragma unroll
  for (int it = 0; it < 16; ++it)
    g2l16(g + it * 4096 + tid * 16, l + it * 4096 + tid * 16);
}

// Wave-per-row normalize -> fp8 e4m3, written in packed+swizzled layout.
// Also zeroes den/posAcc (ws is re-poisoned before every launch).
__global__ __launch_bounds__(256) void normalize_k(
    const float* __restrict__ zi, const float* __restrict__ zj,
    u8* __restrict__ An, float* __restrict__ den, float* __restrict__ posAcc) {
  const int lane = threadIdx.x & 63;
  const int wave = threadIdx.x >> 6;
  const int r = blockIdx.x * 4 + wave;
  const float* src = (r < BS) ? (zi + (size_t)r * D) : (zj + (size_t)(r - BS) * D);
  const float4 v0 = ((const float4*)src)[lane * 2];
  const float4 v1 = ((const float4*)src)[lane * 2 + 1];
  float ss = v0.x * v0.x + v0.y * v0.y + v0.z * v0.z + v0.w * v0.w +
             v1.x * v1.x + v1.y * v1.y + v1.z * v1.z + v1.w * v1.w;
#pragma unroll
  for (int off = 1; off < 64; off <<= 1) ss += __shfl_xor(ss, off);
  const float inv = 1.0f / fmaxf(sqrtf(ss), 1e-8f);
  int lo = __builtin_amdgcn_cvt_pk_fp8_f32(v0.x * inv, v0.y * inv, 0, false);
  lo = __builtin_amdgcn_cvt_pk_fp8_f32(v0.z * inv, v0.w * inv, lo, true);
  int hi = __builtin_amdgcn_cvt_pk_fp8_f32(v1.x * inv, v1.y * inv, 0, false);
  hi = __builtin_amdgcn_cvt_pk_fp8_f32(v1.z * inv, v1.w * inv, hi, true);
  // lane holds chunk L = lane (k = 8*lane .. +8)
  const int r16 = r & 15;
  const int off = ((r >> 4) << 13) + ((lane >> 3) << 10) + (r16 << 6) +
                  ((((lane & 3) ^ (r16 >> 2)) & 3) << 4) + (((lane >> 2) & 1) << 3);
  *(int2*)(An + off) = make_int2(lo, hi);
  if (lane == 0) den[r] = 0.0f;
  if (r == 0 && lane == 0) posAcc[0] = 0.0f;
}

// Persistent full-K GEMM: each block owns a contiguous chunk of ~8 triangle
// tiles. LDS holds full-K A and B strips (64 KB each) -> the K loop has ZERO
// barriers. Per tile: compute -> barrier -> issue next-tile DMA -> epilogue
// (overlaps DMA) -> barrier. A-strip restaged only when bi changes.
__global__ __launch_bounds__(256) void gemm_expsum(
    const u8* __restrict__ An, float* __restrict__ den,
    float* __restrict__ posAcc) {
  __shared__ __align__(16) u8 sA[TILE * D];  // 64 KB
  __shared__ __align__(16) u8 sB[TILE * D];  // 64 KB

  const int tid = threadIdx.x;
  const int lane = tid & 63;
  const int wave = tid >> 6;
  const int wr = wave >> 1;  // wave tile 64x64 within the 128x128 block tile
  const int wc = wave & 1;
  const int fr = lane & 15;
  const int h = lane >> 4;

  // contiguous chunk [t0, t1) of triangle tiles (8 or 9 per block)
  const int t0 = (int)(((long)blockIdx.x * NBLK) >> 8);
  const int t1 = (int)(((long)(blockIdx.x + 1) * NBLK) >> 8);

  int rem = t0, bi = 0;
  while (rem >= NB - bi) { rem -= NB - bi; ++bi; }
  int bj = bi + rem;

  stage_strip(An + (size_t)bi * 65536, sA, tid);
  stage_strip(An + (size_t)bj * 65536, sB, tid);
  __syncthreads();  // drains vmcnt -> tiles resident

  // per-lane fragment base: one b128 per (i, p) covers ks=2p, 2p+1
  const int fbase = fr * 64 + ((h ^ (fr >> 2)) & 3) * 16;
  const u8* pa = sA + wr * 32768 + fbase;
  const u8* pb = sB + wc * 32768 + fbase;

  for (int t = t0; t < t1; ++t) {
    fp32x4 acc[4][4] = {};
    // full-K compute: no barriers; 64 ds_read_b128 + 512 MFMA per wave
#pragma unroll
    for (int p = 0; p < 8; ++p) {
      lx2 a[4], b[4];
#pragma unroll
      for (int i = 0; i < 4; ++i) {
        a[i] = *(const lx2*)(pa + i * 8192 + p * 1024);
        b[i] = *(const lx2*)(pb + i * 8192 + p * 1024);
      }
#pragma unroll
      for (int i = 0; i < 4; ++i)
#pragma unroll
        for (int j = 0; j < 4; ++j)
          acc[i][j] = __builtin_amdgcn_mfma_f32_16x16x32_fp8_fp8(
              a[i][0], b[j][0], acc[i][j], 0, 0, 0);
#pragma unroll
      for (int i = 0; i < 4; ++i)
#pragma unroll
        for (int j = 0; j < 4; ++j)
          acc[i][j] = __builtin_amdgcn_mfma_f32_16x16x32_fp8_fp8(
              a[i][1], b[j][1], acc[i][j], 0, 0, 0);
    }
    __syncthreads();  // every wave done reading sA/sB

    // issue next tile's staging NOW; the DMA runs under the epilogue below
    int nbi = bi, nbj = bj + 1;
    if (nbj == NB) { ++nbi; nbj = nbi; }
    if (t + 1 < t1) {
      if (nbi != bi) stage_strip(An + (size_t)nbi * 65536, sA, tid);
      stage_strip(An + (size_t)nbj * 65536, sB, tid);
    }

    // Epilogue (register-only + atomics; safe while DMA overwrites LDS).
    // C/D layout: col = lane&15, row = (lane>>4)*4 + reg.
    const bool diag = (bi == bj);
    const int rowBase = bi * TILE;
    const int colBase = bj * TILE;
    const int rq = h * 4;
    float posPart = 0.0f;
    float colAcc[4] = {0.0f, 0.0f, 0.0f, 0.0f};
#pragma unroll
    for (int i = 0; i < 4; ++i) {
      const int rbase = rowBase + wr * 64 + i * 16 + rq;
      float rs[4] = {0.0f, 0.0f, 0.0f, 0.0f};
#pragma unroll
      for (int j = 0; j < 4; ++j) {
        const int colg = colBase + wc * 64 + j * 16 + fr;
        fp32x4 v = acc[i][j];
#pragma unroll
        for (int rg = 0; rg < 4; ++rg) {
          const int rowg = rbase + rg;
          const float sv = v[rg] * INV_T;
          float e = __expf(sv);
          if (diag && rowg == colg) e = 0.0f;  // exclude exact diagonal
          rs[rg] += e;
          colAcc[j] += e;
          if (colg == rowg + BS) posPart += sv;  // upper copy; doubled later
        }
      }
#pragma unroll
      for (int rg = 0; rg < 4; ++rg) {
        float s = rs[rg];
        s += __shfl_xor(s, 1);
        s += __shfl_xor(s, 2);
        s += __shfl_xor(s, 4);
        s += __shfl_xor(s, 8);
        if (fr == 0) atomicAdd(&den[rbase + rg], s);
      }
    }
    if (!diag) {
#pragma unroll
      for (int j = 0; j < 4; ++j) {
        float c = colAcc[j];
        c += __shfl_xor(c, 16);
        c += __shfl_xor(c, 32);
        if (h == 0) atomicAdd(&den[colBase + wc * 64 + j * 16 + fr], c);
      }
    }
    posPart += __shfl_xor(posPart, 1);
    posPart += __shfl_xor(posPart, 2);
    posPart += __shfl_xor(posPart, 4);
    posPart += __shfl_xor(posPart, 8);
    posPart += __shfl_xor(posPart, 16);
    posPart += __shfl_xor(posPart, 32);
    if (lane == 0 && posPart != 0.0f) atomicAdd(posAcc, posPart);

    __syncthreads();  // drains vmcnt -> next tile staged; LDS reuse safe
    bi = nbi;
    bj = nbj;
  }
}

__global__ __launch_bounds__(256) void finalize_k(
    const float* __restrict__ den, const float* __restrict__ posAcc,
    float* __restrict__ out) {
  const int t = threadIdx.x;
  float s = 0.0f;
  for (int i = t; i < NROW; i += 256) s += logf(den[i]);
#pragma unroll
  for (int off = 1; off < 64; off <<= 1) s += __shfl_xor(s, off);
  __shared__ float ws[4];
  if ((t & 63) == 0) ws[t >> 6] = s;
  __syncthreads();
  if (t == 0) {
    const float tot = ws[0] + ws[1] + ws[2] + ws[3];
    // each unordered positive pair was counted once -> double it
    out[0] = (tot - 2.0f * posAcc[0]) * (1.0f / (float)NROW);
  }
}

extern "C" void kernel_launch(void* const* d_in, const int* in_sizes, int n_in,
                              void* d_out, int out_size, void* d_ws, size_t ws_size,
                              hipStream_t stream) {
  const float* zi = (const float*)d_in[0];
  const float* zj = (const float*)d_in[1];
  float* out = (float*)d_out;

  u8* An = (u8*)d_ws;                                      // 4 MB packed fp8
  float* den = (float*)((char*)d_ws + (size_t)NROW * D);   // 8192 fp32
  float* posAcc = den + NROW;                              // 1 fp32

  normalize_k<<<NROW / 4, 256, 0, stream>>>(zi, zj, An, den, posAcc);
  gemm_expsum<<<NPBLK, 256, 0, stream>>>(An, den, posAcc);
  finalize_k<<<1, 256, 0, stream>>>(den, posAcc, out);
}